// Round 5
// baseline (150.959 us; speedup 1.0000x reference)
//
#include <hip/hip_runtime.h>
#include <math.h>

#define NB    2
#define NPTS  65536
#define NVSUB 689
#define NJ    24
#define GR    64
#define GRV   (GR*GR*GR)          // 262144 voxels
#define THRESH2 0.0144f           // 0.12^2

// output layout (floats): pts_cano [B,N,1,3] | mask [B,N,1] | w_tf [B,N,4,4]
#define O_PTS  0
#define O_MASK (NB*NPTS*3)        // 393216
#define O_WTF  (O_MASK + NB*NPTS) // 524288

// ---------------- kernel 1: [24][64^3] -> [64^3][24] fp32 transpose ----------
// (exact R1/R2-proven pattern)
__global__ __launch_bounds__(256) void prep_kernel(const float* __restrict__ g,
                                                   float* __restrict__ gt) {
    int vox = blockIdx.x * 256 + threadIdx.x;
    float v[NJ];
#pragma unroll
    for (int c = 0; c < NJ; ++c) v[c] = g[c * GRV + vox];   // coalesced per c
    float4* dst = (float4*)(gt + (size_t)vox * NJ);
#pragma unroll
    for (int c4 = 0; c4 < 6; ++c4)
        dst[c4] = make_float4(v[4*c4+0], v[4*c4+1], v[4*c4+2], v[4*c4+3]);
}

// ---------------- kernel 2: KNN mask only ----------------
// 4 threads per (b,n) pair, each scans a vertex quarter; combine with
// __shfl_xor(1), __shfl_xor(2) inside the 4-thread group; lane qq==0 writes.
__global__ __launch_bounds__(256) void mask_kernel(const float* __restrict__ pts_in,
                                                   const float* __restrict__ vs,
                                                   float* __restrict__ out) {
    __shared__ float4 s_vs[NVSUB];
    const int tid = threadIdx.x;
    for (int i = tid; i < NVSUB; i += 256) {
        float x = vs[i * 3 + 0], y = vs[i * 3 + 1], z = vs[i * 3 + 2];
        s_vs[i] = make_float4(x, y, z, x * x + y * y + z * z);
    }
    __syncthreads();

    const int t  = blockIdx.x * 256 + tid;
    const int p  = t >> 2;          // pair id in [0, 131072)
    const int qq = t & 3;           // vertex quarter
    const int b  = p >> 16;
    const int n  = p & (NPTS - 1);

    const float* P = pts_in + ((size_t)b * NPTS + n) * 3;
    const float px = P[0], py = P[1], pz = P[2];

    const int vbeg = qq * 173;
    const int vend = min(vbeg + 173, NVSUB);
    float ma = 3.4e38f, mb = 3.4e38f;
    int v = vbeg;
    for (; v + 2 <= vend; v += 2) {
        float4 t0 = s_vs[v];
        float4 t1 = s_vs[v + 1];
        ma = fminf(ma, fmaf(-2.f, px * t0.x + py * t0.y + pz * t0.z, t0.w));
        mb = fminf(mb, fmaf(-2.f, px * t1.x + py * t1.y + pz * t1.z, t1.w));
    }
    if (v < vend) {
        float4 t0 = s_vs[v];
        ma = fminf(ma, fmaf(-2.f, px * t0.x + py * t0.y + pz * t0.z, t0.w));
    }
    float mm = fminf(ma, mb);
    mm = fminf(mm, __shfl_xor(mm, 1));
    mm = fminf(mm, __shfl_xor(mm, 2));
    if (qq == 0) {
        float dist2 = mm + px * px + py * py + pz * pz;
        out[O_MASK + p] = (dist2 < THRESH2) ? 1.f : 0.f;
    }
}

// ---------------- kernel 3: trilinear + skinning (R2-proven phase-2 body) ----
// Block = 256 threads = 128 pairs x 2 channel-halves.  Grid = 1024 blocks;
// batch boundary (p=65536) falls exactly at block 512, so b is block-uniform.
__global__ __launch_bounds__(256) void deform_kernel(
    const float* __restrict__ pts_in,    // [2,N,3]
    const float* __restrict__ shape_off, // [6890,3]
    const int*   __restrict__ init_idx,  // [N,3]
    const float* __restrict__ init_bar,  // [N,3]
    const float* __restrict__ gT,        // [64^3][24] fp32
    const float* __restrict__ tfs,       // [2,24,4,4]
    const float* __restrict__ gscale,    // [3]
    const float* __restrict__ goff,      // [3]
    float* __restrict__ out) {
    __shared__ float s_part[128][20];   // 16 acc + wsum (stride 20, 16B-aligned rows)

    const int tid = threadIdx.x;
    const int pl  = tid & 127;          // pair slot in block
    const int hf  = tid >> 7;           // channel half
    const int p   = blockIdx.x * 128 + pl;
    const int b   = p >> 16;            // block-uniform (boundary at block 512)
    const int n   = p & (NPTS - 1);

    const float* P = pts_in + ((size_t)b * NPTS + n) * 3;
    const float px = P[0], py = P[1], pz = P[2];

    // barycentric shape offset (computed identically by both halves)
    int i0 = init_idx[n * 3 + 0] * 3;
    int i1 = init_idx[n * 3 + 1] * 3;
    int i2 = init_idx[n * 3 + 2] * 3;
    float b0 = init_bar[n * 3 + 0], b1 = init_bar[n * 3 + 1], b2 = init_bar[n * 3 + 2];
    float qx = px + b0 * shape_off[i0 + 0] + b1 * shape_off[i1 + 0] + b2 * shape_off[i2 + 0];
    float qy = py + b0 * shape_off[i0 + 1] + b1 * shape_off[i1 + 1] + b2 * shape_off[i2 + 1];
    float qz = pz + b0 * shape_off[i0 + 2] + b1 * shape_off[i1 + 2] + b2 * shape_off[i2 + 2];

    float ccx = fminf(fmaxf((qx - goff[0]) * gscale[0], -1.f), 1.f);
    float ccy = fminf(fmaxf((qy - goff[1]) * gscale[1], -1.f), 1.f);
    float ccz = fminf(fmaxf((qz - goff[2]) * gscale[2], -1.f), 1.f);
    float x = (ccx + 1.f) * 0.5f * (GR - 1);
    float y = (ccy + 1.f) * 0.5f * (GR - 1);
    float z = (ccz + 1.f) * 0.5f * (GR - 1);
    int x0 = (int)floorf(x), y0 = (int)floorf(y), z0 = (int)floorf(z);
    int x1 = min(x0 + 1, GR - 1), y1 = min(y0 + 1, GR - 1), z1 = min(z0 + 1, GR - 1);
    float fx = x - (float)x0, fy = y - (float)y0, fz = z - (float)z0;
    float wxa[2] = {1.f - fx, fx}, wya[2] = {1.f - fy, fy}, wza[2] = {1.f - fz, fz};

    float w[12];
#pragma unroll
    for (int c = 0; c < 12; ++c) w[c] = 0.f;

#pragma unroll
    for (int ci = 0; ci < 8; ++ci) {
        int xi = (ci & 1) ? x1 : x0;
        int yi = (ci & 2) ? y1 : y0;
        int zi = (ci & 4) ? z1 : z0;
        float wt = wxa[ci & 1] * wya[(ci >> 1) & 1] * wza[(ci >> 2) & 1];
        int vox = (zi * GR + yi) * GR + xi;
        const float4* g4 = (const float4*)(gT + (size_t)vox * NJ + hf * 12);
        float4 g0 = g4[0], g1 = g4[1], g2 = g4[2];
        w[0]  = fmaf(wt, g0.x, w[0]);  w[1]  = fmaf(wt, g0.y, w[1]);
        w[2]  = fmaf(wt, g0.z, w[2]);  w[3]  = fmaf(wt, g0.w, w[3]);
        w[4]  = fmaf(wt, g1.x, w[4]);  w[5]  = fmaf(wt, g1.y, w[5]);
        w[6]  = fmaf(wt, g1.z, w[6]);  w[7]  = fmaf(wt, g1.w, w[7]);
        w[8]  = fmaf(wt, g2.x, w[8]);  w[9]  = fmaf(wt, g2.y, w[9]);
        w[10] = fmaf(wt, g2.z, w[10]); w[11] = fmaf(wt, g2.w, w[11]);
    }
    float wsum = 0.f;
#pragma unroll
    for (int c = 0; c < 12; ++c) wsum += w[c];

    // partial skinning with uniform scalar-cached tfs rows (b, hf wave-uniform)
    const int bu  = __builtin_amdgcn_readfirstlane(b);
    const int hfu = __builtin_amdgcn_readfirstlane(hf);
    const float* tb = tfs + (size_t)(bu * NJ + hfu * 12) * 16;
    float acc[16];
#pragma unroll
    for (int k = 0; k < 16; ++k) acc[k] = 0.f;
#pragma unroll
    for (int jj = 0; jj < 12; ++jj) {
        float wj = w[jj];
#pragma unroll
        for (int k = 0; k < 16; ++k) acc[k] = fmaf(wj, tb[jj * 16 + k], acc[k]);
    }

    if (hf == 1) {
        float* sp = &s_part[pl][0];
        ((float4*)sp)[0] = make_float4(acc[0],  acc[1],  acc[2],  acc[3]);
        ((float4*)sp)[1] = make_float4(acc[4],  acc[5],  acc[6],  acc[7]);
        ((float4*)sp)[2] = make_float4(acc[8],  acc[9],  acc[10], acc[11]);
        ((float4*)sp)[3] = make_float4(acc[12], acc[13], acc[14], acc[15]);
        sp[16] = wsum;
    }
    __syncthreads();

    if (hf == 0) {
        const float* sp = &s_part[pl][0];
        float4 q0 = ((const float4*)sp)[0], q1 = ((const float4*)sp)[1];
        float4 q2 = ((const float4*)sp)[2], q3 = ((const float4*)sp)[3];
        acc[0] += q0.x;  acc[1] += q0.y;  acc[2] += q0.z;  acc[3] += q0.w;
        acc[4] += q1.x;  acc[5] += q1.y;  acc[6] += q1.z;  acc[7] += q1.w;
        acc[8] += q2.x;  acc[9] += q2.y;  acc[10] += q2.z; acc[11] += q2.w;
        acc[12] += q3.x; acc[13] += q3.y; acc[14] += q3.z; acc[15] += q3.w;
        wsum += sp[16];
        float inv = __builtin_amdgcn_rcpf(fmaxf(wsum, 1e-6f));
#pragma unroll
        for (int k = 0; k < 16; ++k) acc[k] *= inv;

        float ox = acc[0] * qx + acc[1] * qy + acc[2]  * qz + acc[3];
        float oy = acc[4] * qx + acc[5] * qy + acc[6]  * qz + acc[7];
        float oz = acc[8] * qx + acc[9] * qy + acc[10] * qz + acc[11];

        size_t bn = (size_t)p;   // p == b*NPTS + n
        out[O_PTS + bn * 3 + 0] = ox;
        out[O_PTS + bn * 3 + 1] = oy;
        out[O_PTS + bn * 3 + 2] = oz;
        float4* wt4 = (float4*)(out + O_WTF + bn * 16);
        wt4[0] = make_float4(acc[0],  acc[1],  acc[2],  acc[3]);
        wt4[1] = make_float4(acc[4],  acc[5],  acc[6],  acc[7]);
        wt4[2] = make_float4(acc[8],  acc[9],  acc[10], acc[11]);
        wt4[3] = make_float4(acc[12], acc[13], acc[14], acc[15]);
    }
}

// ---------------- fallback (ws too small): simple fp32 path ----------------
__global__ __launch_bounds__(256) void snarf_fallback(
    const float* __restrict__ pts_in, const float* __restrict__ vs,
    const float* __restrict__ shape_off, const int* __restrict__ init_idx,
    const float* __restrict__ init_bar, const float* __restrict__ grid,
    const float* __restrict__ tfs, const float* __restrict__ gscale,
    const float* __restrict__ goff, float* __restrict__ out) {
    const int n = blockIdx.x * 256 + threadIdx.x;
    for (int b = 0; b < NB; ++b) {
        float px = pts_in[((size_t)b * NPTS + n) * 3 + 0];
        float py = pts_in[((size_t)b * NPTS + n) * 3 + 1];
        float pz = pts_in[((size_t)b * NPTS + n) * 3 + 2];
        float mm = 3.4e38f;
        for (int v = 0; v < NVSUB; ++v) {
            float dx = px - vs[v * 3 + 0], dy = py - vs[v * 3 + 1], dz = pz - vs[v * 3 + 2];
            mm = fminf(mm, dx * dx + dy * dy + dz * dz);
        }
        int i0 = init_idx[n * 3 + 0] * 3, i1 = init_idx[n * 3 + 1] * 3, i2 = init_idx[n * 3 + 2] * 3;
        float b0 = init_bar[n * 3 + 0], b1 = init_bar[n * 3 + 1], b2 = init_bar[n * 3 + 2];
        float qx = px + b0 * shape_off[i0 + 0] + b1 * shape_off[i1 + 0] + b2 * shape_off[i2 + 0];
        float qy = py + b0 * shape_off[i0 + 1] + b1 * shape_off[i1 + 1] + b2 * shape_off[i2 + 1];
        float qz = pz + b0 * shape_off[i0 + 2] + b1 * shape_off[i1 + 2] + b2 * shape_off[i2 + 2];
        float cx = fminf(fmaxf((qx - goff[0]) * gscale[0], -1.f), 1.f);
        float cy = fminf(fmaxf((qy - goff[1]) * gscale[1], -1.f), 1.f);
        float cz = fminf(fmaxf((qz - goff[2]) * gscale[2], -1.f), 1.f);
        float x = (cx + 1.f) * 0.5f * (GR - 1), y = (cy + 1.f) * 0.5f * (GR - 1), z = (cz + 1.f) * 0.5f * (GR - 1);
        int x0 = (int)floorf(x), y0 = (int)floorf(y), z0 = (int)floorf(z);
        int x1 = min(x0 + 1, GR - 1), y1 = min(y0 + 1, GR - 1), z1 = min(z0 + 1, GR - 1);
        float fx = x - x0, fy = y - y0, fz = z - z0;
        float wxa[2] = {1.f - fx, fx}, wya[2] = {1.f - fy, fy}, wza[2] = {1.f - fz, fz};
        float w[NJ];
        for (int c = 0; c < NJ; ++c) w[c] = 0.f;
        for (int ci = 0; ci < 8; ++ci) {
            int xi = (ci & 1) ? x1 : x0, yi = (ci & 2) ? y1 : y0, zi = (ci & 4) ? z1 : z0;
            float wt = wxa[ci & 1] * wya[(ci >> 1) & 1] * wza[(ci >> 2) & 1];
            int vox = (zi * GR + yi) * GR + xi;
            for (int c = 0; c < NJ; ++c) w[c] = fmaf(wt, grid[c * GRV + vox], w[c]);
        }
        float s = 0.f;
        for (int c = 0; c < NJ; ++c) s += w[c];
        float inv = 1.f / fmaxf(s, 1e-6f);
        float acc[16];
        for (int k = 0; k < 16; ++k) acc[k] = 0.f;
        for (int j = 0; j < NJ; ++j) {
            float wj = w[j] * inv;
            for (int k = 0; k < 16; ++k) acc[k] = fmaf(wj, tfs[(b * NJ + j) * 16 + k], acc[k]);
        }
        size_t bn = (size_t)b * NPTS + n;
        out[O_PTS + bn * 3 + 0] = acc[0] * qx + acc[1] * qy + acc[2] * qz + acc[3];
        out[O_PTS + bn * 3 + 1] = acc[4] * qx + acc[5] * qy + acc[6] * qz + acc[7];
        out[O_PTS + bn * 3 + 2] = acc[8] * qx + acc[9] * qy + acc[10] * qz + acc[11];
        out[O_MASK + bn] = (mm < THRESH2) ? 1.f : 0.f;
        for (int k = 0; k < 16; ++k) out[O_WTF + bn * 16 + k] = acc[k];
    }
}

extern "C" void kernel_launch(void* const* d_in, const int* in_sizes, int n_in,
                              void* d_out, int out_size, void* d_ws, size_t ws_size,
                              hipStream_t stream) {
    const float* pts_in    = (const float*)d_in[0];
    const float* vs        = (const float*)d_in[1];
    const float* shape_off = (const float*)d_in[2];
    const int*   init_idx  = (const int*)d_in[3];
    const float* init_bar  = (const float*)d_in[4];
    const float* lbs       = (const float*)d_in[5];
    const float* tfs       = (const float*)d_in[6];
    const float* gs        = (const float*)d_in[7];
    const float* go        = (const float*)d_in[8];
    float* out = (float*)d_out;

    const size_t needed = (size_t)GRV * NJ * sizeof(float);  // ~25.2 MB
    if (ws_size >= needed) {
        float* gT = (float*)d_ws;
        prep_kernel<<<GRV / 256, 256, 0, stream>>>(lbs, gT);
        mask_kernel<<<(NB * NPTS * 4) / 256, 256, 0, stream>>>(pts_in, vs, out);
        deform_kernel<<<(NB * NPTS) / 128, 256, 0, stream>>>(
            pts_in, shape_off, init_idx, init_bar, gT, tfs, gs, go, out);
    } else {
        snarf_fallback<<<NPTS / 256, 256, 0, stream>>>(
            pts_in, vs, shape_off, init_idx, init_bar, lbs, tfs, gs, go, out);
    }
}

// Round 7
// 140.069 us; speedup vs baseline: 1.0777x; 1.0777x over previous
//
#include <hip/hip_runtime.h>
#include <math.h>

#define NB    2
#define NPTS  65536
#define NVSUB 689
#define NJ    24
#define GR    64
#define GRV   (GR*GR*GR)          // 262144 voxels
#define THRESH2 0.0144f           // 0.12^2

// output layout (floats): pts_cano [B,N,1,3] | mask [B,N,1] | w_tf [B,N,4,4]
#define O_PTS  0
#define O_MASK (NB*NPTS*3)        // 393216
#define O_WTF  (O_MASK + NB*NPTS) // 524288

#define PREP_BLOCKS (GRV / 256)   // 1024
#define MASK_BLOCKS ((NB * NPTS * 4) / 256)  // 2048

// ---------------- fat kernel 1: prep (transpose) ∥ mask (KNN) ----------------
// blocks [0, 1024): [24][64^3] -> [64^3][24] fp32 transpose (R1/R2/R5-proven)
// blocks [1024, 3072): KNN mask, 4 threads per (b,n) pair (R5-proven body)
__global__ __launch_bounds__(256) void prep_mask_kernel(
    const float* __restrict__ g, float* __restrict__ gt,
    const float* __restrict__ pts_in, const float* __restrict__ vs,
    float* __restrict__ out) {
    __shared__ float4 s_vs[NVSUB];
    const int tid = threadIdx.x;

    if (blockIdx.x < PREP_BLOCKS) {
        // ---- prep ----
        int vox = blockIdx.x * 256 + tid;
        float v[NJ];
#pragma unroll
        for (int c = 0; c < NJ; ++c) v[c] = g[c * GRV + vox];   // coalesced per c
        float4* dst = (float4*)(gt + (size_t)vox * NJ);
#pragma unroll
        for (int c4 = 0; c4 < 6; ++c4)
            dst[c4] = make_float4(v[4*c4+0], v[4*c4+1], v[4*c4+2], v[4*c4+3]);
        return;
    }

    // ---- mask ----
    for (int i = tid; i < NVSUB; i += 256) {
        float x = vs[i * 3 + 0], y = vs[i * 3 + 1], z = vs[i * 3 + 2];
        s_vs[i] = make_float4(x, y, z, x * x + y * y + z * z);
    }
    __syncthreads();

    const int t  = (blockIdx.x - PREP_BLOCKS) * 256 + tid;
    const int p  = t >> 2;          // pair id in [0, 131072)
    const int qq = t & 3;           // vertex quarter
    const int b  = p >> 16;
    const int n  = p & (NPTS - 1);

    const float* P = pts_in + ((size_t)b * NPTS + n) * 3;
    const float px = P[0], py = P[1], pz = P[2];

    const int vbeg = qq * 173;
    const int vend = min(vbeg + 173, NVSUB);
    float ma = 3.4e38f, mb = 3.4e38f;
    int v = vbeg;
    for (; v + 2 <= vend; v += 2) {
        float4 t0 = s_vs[v];
        float4 t1 = s_vs[v + 1];
        ma = fminf(ma, fmaf(-2.f, px * t0.x + py * t0.y + pz * t0.z, t0.w));
        mb = fminf(mb, fmaf(-2.f, px * t1.x + py * t1.y + pz * t1.z, t1.w));
    }
    if (v < vend) {
        float4 t0 = s_vs[v];
        ma = fminf(ma, fmaf(-2.f, px * t0.x + py * t0.y + pz * t0.z, t0.w));
    }
    float mm = fminf(ma, mb);
    mm = fminf(mm, __shfl_xor(mm, 1));
    mm = fminf(mm, __shfl_xor(mm, 2));
    if (qq == 0) {
        float dist2 = mm + px * px + py * py + pz * pz;
        out[O_MASK + p] = (dist2 < THRESH2) ? 1.f : 0.f;
    }
}

// ---------------- kernel 2: trilinear + skinning, 4 threads / pair ----------
// t -> pair p = t>>2, joint-quarter q = t&3 (6 joints each).  Grid loads are
// float2 (24B/corner/thread); tfs staged in LDS, read at 4-distinct broadcast
// addresses (conflict-free); 16 acc + wsum merged across the quad via
// __shfl_xor(1/2); lane q==0 normalizes and writes pts + w_tf.
__global__ __launch_bounds__(256, 6) void deform_kernel(
    const float* __restrict__ pts_in,    // [2,N,3]
    const float* __restrict__ shape_off, // [6890,3]
    const int*   __restrict__ init_idx,  // [N,3]
    const float* __restrict__ init_bar,  // [N,3]
    const float* __restrict__ gT,        // [64^3][24] fp32
    const float* __restrict__ tfs,       // [2,24,4,4]
    const float* __restrict__ gscale,    // [3]
    const float* __restrict__ goff,      // [3]
    float* __restrict__ out) {
    __shared__ float s_tfs[NB * NJ * 16];   // 3 KB

    const int tid = threadIdx.x;
    for (int i = tid; i < NB * NJ * 16; i += 256) s_tfs[i] = tfs[i];
    __syncthreads();

    const int t = blockIdx.x * 256 + tid;
    const int p = t >> 2;           // pair id
    const int q = t & 3;            // joint quarter
    const int b = p >> 16;          // block-uniform (boundary at block 1024)
    const int n = p & (NPTS - 1);

    const float* P = pts_in + ((size_t)b * NPTS + n) * 3;
    const float px = P[0], py = P[1], pz = P[2];

    // barycentric shape offset (all 4 lanes of the quad compute identically)
    int i0 = init_idx[n * 3 + 0] * 3;
    int i1 = init_idx[n * 3 + 1] * 3;
    int i2 = init_idx[n * 3 + 2] * 3;
    float b0 = init_bar[n * 3 + 0], b1 = init_bar[n * 3 + 1], b2 = init_bar[n * 3 + 2];
    float qx = px + b0 * shape_off[i0 + 0] + b1 * shape_off[i1 + 0] + b2 * shape_off[i2 + 0];
    float qy = py + b0 * shape_off[i0 + 1] + b1 * shape_off[i1 + 1] + b2 * shape_off[i2 + 1];
    float qz = pz + b0 * shape_off[i0 + 2] + b1 * shape_off[i1 + 2] + b2 * shape_off[i2 + 2];

    float ccx = fminf(fmaxf((qx - goff[0]) * gscale[0], -1.f), 1.f);
    float ccy = fminf(fmaxf((qy - goff[1]) * gscale[1], -1.f), 1.f);
    float ccz = fminf(fmaxf((qz - goff[2]) * gscale[2], -1.f), 1.f);
    float x = (ccx + 1.f) * 0.5f * (GR - 1);
    float y = (ccy + 1.f) * 0.5f * (GR - 1);
    float z = (ccz + 1.f) * 0.5f * (GR - 1);
    int x0 = (int)floorf(x), y0 = (int)floorf(y), z0 = (int)floorf(z);
    int x1 = min(x0 + 1, GR - 1), y1 = min(y0 + 1, GR - 1), z1 = min(z0 + 1, GR - 1);
    float fx = x - (float)x0, fy = y - (float)y0, fz = z - (float)z0;
    float wxa[2] = {1.f - fx, fx}, wya[2] = {1.f - fy, fy}, wza[2] = {1.f - fz, fz};

    float w[6];
#pragma unroll
    for (int c = 0; c < 6; ++c) w[c] = 0.f;

#pragma unroll
    for (int ci = 0; ci < 8; ++ci) {
        int xi = (ci & 1) ? x1 : x0;
        int yi = (ci & 2) ? y1 : y0;
        int zi = (ci & 4) ? z1 : z0;
        float wt = wxa[ci & 1] * wya[(ci >> 1) & 1] * wza[(ci >> 2) & 1];
        int vox = (zi * GR + yi) * GR + xi;
        const float2* g2 = (const float2*)(gT + (size_t)vox * NJ + q * 6);
        float2 ga = g2[0], gb = g2[1], gc = g2[2];
        w[0] = fmaf(wt, ga.x, w[0]); w[1] = fmaf(wt, ga.y, w[1]);
        w[2] = fmaf(wt, gb.x, w[2]); w[3] = fmaf(wt, gb.y, w[3]);
        w[4] = fmaf(wt, gc.x, w[4]); w[5] = fmaf(wt, gc.y, w[5]);
    }
    float wsum = w[0] + w[1] + w[2] + w[3] + w[4] + w[5];

    // partial skinning over this quarter's 6 joints; tfs rows from LDS
    // (address depends only on q -> 4 distinct addresses -> broadcast, no conflict)
    float4 A0 = make_float4(0.f, 0.f, 0.f, 0.f);
    float4 A1 = A0, A2 = A0, A3 = A0;
    const float4* tb = (const float4*)(s_tfs + (size_t)(b * NJ + q * 6) * 16);
#pragma unroll
    for (int jj = 0; jj < 6; ++jj) {
        float wj = w[jj];
        float4 r0 = tb[jj * 4 + 0], r1 = tb[jj * 4 + 1];
        float4 r2 = tb[jj * 4 + 2], r3 = tb[jj * 4 + 3];
        A0.x = fmaf(wj, r0.x, A0.x); A0.y = fmaf(wj, r0.y, A0.y);
        A0.z = fmaf(wj, r0.z, A0.z); A0.w = fmaf(wj, r0.w, A0.w);
        A1.x = fmaf(wj, r1.x, A1.x); A1.y = fmaf(wj, r1.y, A1.y);
        A1.z = fmaf(wj, r1.z, A1.z); A1.w = fmaf(wj, r1.w, A1.w);
        A2.x = fmaf(wj, r2.x, A2.x); A2.y = fmaf(wj, r2.y, A2.y);
        A2.z = fmaf(wj, r2.z, A2.z); A2.w = fmaf(wj, r2.w, A2.w);
        A3.x = fmaf(wj, r3.x, A3.x); A3.y = fmaf(wj, r3.y, A3.y);
        A3.z = fmaf(wj, r3.z, A3.z); A3.w = fmaf(wj, r3.w, A3.w);
    }

    // quad reduction (lanes q^1, q^2 are the same pair)
#define QRED(v) v += __shfl_xor(v, 1); v += __shfl_xor(v, 2)
    QRED(A0.x); QRED(A0.y); QRED(A0.z); QRED(A0.w);
    QRED(A1.x); QRED(A1.y); QRED(A1.z); QRED(A1.w);
    QRED(A2.x); QRED(A2.y); QRED(A2.z); QRED(A2.w);
    QRED(A3.x); QRED(A3.y); QRED(A3.z); QRED(A3.w);
    QRED(wsum);
#undef QRED

    if (q == 0) {
        float inv = __builtin_amdgcn_rcpf(fmaxf(wsum, 1e-6f));
        A0.x *= inv; A0.y *= inv; A0.z *= inv; A0.w *= inv;
        A1.x *= inv; A1.y *= inv; A1.z *= inv; A1.w *= inv;
        A2.x *= inv; A2.y *= inv; A2.z *= inv; A2.w *= inv;
        A3.x *= inv; A3.y *= inv; A3.z *= inv; A3.w *= inv;

        float ox = A0.x * qx + A0.y * qy + A0.z * qz + A0.w;
        float oy = A1.x * qx + A1.y * qy + A1.z * qz + A1.w;
        float oz = A2.x * qx + A2.y * qy + A2.z * qz + A2.w;

        size_t bn = (size_t)p;   // p == b*NPTS + n
        out[O_PTS + bn * 3 + 0] = ox;
        out[O_PTS + bn * 3 + 1] = oy;
        out[O_PTS + bn * 3 + 2] = oz;
        float4* wt4 = (float4*)(out + O_WTF + bn * 16);
        wt4[0] = A0; wt4[1] = A1; wt4[2] = A2; wt4[3] = A3;
    }
}

// ---------------- fallback (ws too small): simple fp32 path ----------------
__global__ __launch_bounds__(256) void snarf_fallback(
    const float* __restrict__ pts_in, const float* __restrict__ vs,
    const float* __restrict__ shape_off, const int* __restrict__ init_idx,
    const float* __restrict__ init_bar, const float* __restrict__ grid,
    const float* __restrict__ tfs, const float* __restrict__ gscale,
    const float* __restrict__ goff, float* __restrict__ out) {
    const int n = blockIdx.x * 256 + threadIdx.x;
    for (int b = 0; b < NB; ++b) {
        float px = pts_in[((size_t)b * NPTS + n) * 3 + 0];
        float py = pts_in[((size_t)b * NPTS + n) * 3 + 1];
        float pz = pts_in[((size_t)b * NPTS + n) * 3 + 2];
        float mm = 3.4e38f;
        for (int v = 0; v < NVSUB; ++v) {
            float dx = px - vs[v * 3 + 0], dy = py - vs[v * 3 + 1], dz = pz - vs[v * 3 + 2];
            mm = fminf(mm, dx * dx + dy * dy + dz * dz);
        }
        int i0 = init_idx[n * 3 + 0] * 3, i1 = init_idx[n * 3 + 1] * 3, i2 = init_idx[n * 3 + 2] * 3;
        float b0 = init_bar[n * 3 + 0], b1 = init_bar[n * 3 + 1], b2 = init_bar[n * 3 + 2];
        float qx = px + b0 * shape_off[i0 + 0] + b1 * shape_off[i1 + 0] + b2 * shape_off[i2 + 0];
        float qy = py + b0 * shape_off[i0 + 1] + b1 * shape_off[i1 + 1] + b2 * shape_off[i2 + 1];
        float qz = pz + b0 * shape_off[i0 + 2] + b1 * shape_off[i1 + 2] + b2 * shape_off[i2 + 2];
        float cx = fminf(fmaxf((qx - goff[0]) * gscale[0], -1.f), 1.f);
        float cy = fminf(fmaxf((qy - goff[1]) * gscale[1], -1.f), 1.f);
        float cz = fminf(fmaxf((qz - goff[2]) * gscale[2], -1.f), 1.f);
        float x = (cx + 1.f) * 0.5f * (GR - 1), y = (cy + 1.f) * 0.5f * (GR - 1), z = (cz + 1.f) * 0.5f * (GR - 1);
        int x0 = (int)floorf(x), y0 = (int)floorf(y), z0 = (int)floorf(z);
        int x1 = min(x0 + 1, GR - 1), y1 = min(y0 + 1, GR - 1), z1 = min(z0 + 1, GR - 1);
        float fx = x - x0, fy = y - y0, fz = z - z0;
        float wxa[2] = {1.f - fx, fx}, wya[2] = {1.f - fy, fy}, wza[2] = {1.f - fz, fz};
        float w[NJ];
        for (int c = 0; c < NJ; ++c) w[c] = 0.f;
        for (int ci = 0; ci < 8; ++ci) {
            int xi = (ci & 1) ? x1 : x0, yi = (ci & 2) ? y1 : y0, zi = (ci & 4) ? z1 : z0;
            float wt = wxa[ci & 1] * wya[(ci >> 1) & 1] * wza[(ci >> 2) & 1];
            int vox = (zi * GR + yi) * GR + xi;
            for (int c = 0; c < NJ; ++c) w[c] = fmaf(wt, grid[c * GRV + vox], w[c]);
        }
        float s = 0.f;
        for (int c = 0; c < NJ; ++c) s += w[c];
        float inv = 1.f / fmaxf(s, 1e-6f);
        float acc[16];
        for (int k = 0; k < 16; ++k) acc[k] = 0.f;
        for (int j = 0; j < NJ; ++j) {
            float wj = w[j] * inv;
            for (int k = 0; k < 16; ++k) acc[k] = fmaf(wj, tfs[(b * NJ + j) * 16 + k], acc[k]);
        }
        size_t bn = (size_t)b * NPTS + n;
        out[O_PTS + bn * 3 + 0] = acc[0] * qx + acc[1] * qy + acc[2] * qz + acc[3];
        out[O_PTS + bn * 3 + 1] = acc[4] * qx + acc[5] * qy + acc[6] * qz + acc[7];
        out[O_PTS + bn * 3 + 2] = acc[8] * qx + acc[9] * qy + acc[10] * qz + acc[11];
        out[O_MASK + bn] = (mm < THRESH2) ? 1.f : 0.f;
        for (int k = 0; k < 16; ++k) out[O_WTF + bn * 16 + k] = acc[k];
    }
}

extern "C" void kernel_launch(void* const* d_in, const int* in_sizes, int n_in,
                              void* d_out, int out_size, void* d_ws, size_t ws_size,
                              hipStream_t stream) {
    const float* pts_in    = (const float*)d_in[0];
    const float* vs        = (const float*)d_in[1];
    const float* shape_off = (const float*)d_in[2];
    const int*   init_idx  = (const int*)d_in[3];
    const float* init_bar  = (const float*)d_in[4];
    const float* lbs       = (const float*)d_in[5];
    const float* tfs       = (const float*)d_in[6];
    const float* gs        = (const float*)d_in[7];
    const float* go        = (const float*)d_in[8];
    float* out = (float*)d_out;

    const size_t needed = (size_t)GRV * NJ * sizeof(float);  // ~25.2 MB
    if (ws_size >= needed) {
        float* gT = (float*)d_ws;
        prep_mask_kernel<<<PREP_BLOCKS + MASK_BLOCKS, 256, 0, stream>>>(
            lbs, gT, pts_in, vs, out);
        deform_kernel<<<(NB * NPTS * 4) / 256, 256, 0, stream>>>(
            pts_in, shape_off, init_idx, init_bar, gT, tfs, gs, go, out);
    } else {
        snarf_fallback<<<NPTS / 256, 256, 0, stream>>>(
            pts_in, vs, shape_off, init_idx, init_bar, lbs, tfs, gs, go, out);
    }
}

// Round 9
// 139.192 us; speedup vs baseline: 1.0845x; 1.0063x over previous
//
#include <hip/hip_runtime.h>
#include <math.h>

#define NB    2
#define NPTS  65536
#define NVSUB 689
#define NJ    24
#define GR    64
#define GRV   (GR*GR*GR)          // 262144 voxels
#define THRESH2 0.0144f           // 0.12^2
#define CSTRIDE 32                // padded cell stride in floats (128B line)

// output layout (floats): pts_cano [B,N,1,3] | mask [B,N,1] | w_tf [B,N,4,4]
#define O_PTS  0
#define O_MASK (NB*NPTS*3)        // 393216
#define O_WTF  (O_MASK + NB*NPTS) // 524288

#define PREP_BLOCKS (GRV / 256)           // 1024
#define MASK_BLOCKS ((NPTS * 4) / 256)    // 1024 (4 threads per n, 2 chains each)

// ---------------- fat kernel 1: prep (transpose, 128B-padded) ∥ mask (KNN) ---
// blocks [0, 1024): [24][64^3] -> [64^3][32-padded] fp32 transpose
// blocks [1024, 2048): KNN mask; thread t -> n = t>>2, quarter qq = t&3,
//   chains b0+b1 with unroll-2 (R2-proven 4-chain body); quad-combine shfl_xor.
__global__ __launch_bounds__(256) void prep_mask_kernel(
    const float* __restrict__ g, float* __restrict__ gt,
    const float* __restrict__ pts_in, const float* __restrict__ vs,
    float* __restrict__ out) {
    __shared__ float4 s_vs[NVSUB];
    const int tid = threadIdx.x;

    if (blockIdx.x < PREP_BLOCKS) {
        // ---- prep ----
        int vox = blockIdx.x * 256 + tid;
        float v[NJ];
#pragma unroll
        for (int c = 0; c < NJ; ++c) v[c] = g[c * GRV + vox];   // coalesced per c
        float4* dst = (float4*)(gt + (size_t)vox * CSTRIDE);
#pragma unroll
        for (int c4 = 0; c4 < 6; ++c4)
            dst[c4] = make_float4(v[4*c4+0], v[4*c4+1], v[4*c4+2], v[4*c4+3]);
        return;
    }

    // ---- mask ----
    for (int i = tid; i < NVSUB; i += 256) {
        float x = vs[i * 3 + 0], y = vs[i * 3 + 1], z = vs[i * 3 + 2];
        s_vs[i] = make_float4(x, y, z, x * x + y * y + z * z);
    }
    __syncthreads();

    const int t  = (blockIdx.x - PREP_BLOCKS) * 256 + tid;
    const int n  = t >> 2;          // point id in [0, 65536)
    const int qq = t & 3;           // vertex quarter

    const float* P0 = pts_in + (size_t)n * 3;
    const float* P1 = pts_in + (size_t)(NPTS + n) * 3;
    const float ax = P0[0], ay = P0[1], az = P0[2];
    const float bx = P1[0], by = P1[1], bz = P1[2];

    const int vbeg = qq * 173;
    const int vend = min(vbeg + 173, NVSUB);
    float m0a = 3.4e38f, m0b = 3.4e38f, m1a = 3.4e38f, m1b = 3.4e38f;
    int v = vbeg;
    for (; v + 2 <= vend; v += 2) {
        float4 t0 = s_vs[v];
        float4 t1 = s_vs[v + 1];
        m0a = fminf(m0a, fmaf(-2.f, ax * t0.x + ay * t0.y + az * t0.z, t0.w));
        m1a = fminf(m1a, fmaf(-2.f, bx * t0.x + by * t0.y + bz * t0.z, t0.w));
        m0b = fminf(m0b, fmaf(-2.f, ax * t1.x + ay * t1.y + az * t1.z, t1.w));
        m1b = fminf(m1b, fmaf(-2.f, bx * t1.x + by * t1.y + bz * t1.z, t1.w));
    }
    if (v < vend) {
        float4 t0 = s_vs[v];
        m0a = fminf(m0a, fmaf(-2.f, ax * t0.x + ay * t0.y + az * t0.z, t0.w));
        m1a = fminf(m1a, fmaf(-2.f, bx * t0.x + by * t0.y + bz * t0.z, t0.w));
    }
    float mm0 = fminf(m0a, m0b);
    float mm1 = fminf(m1a, m1b);
    mm0 = fminf(mm0, __shfl_xor(mm0, 1));
    mm0 = fminf(mm0, __shfl_xor(mm0, 2));
    mm1 = fminf(mm1, __shfl_xor(mm1, 1));
    mm1 = fminf(mm1, __shfl_xor(mm1, 2));
    if (qq == 0) {
        float d0 = mm0 + ax * ax + ay * ay + az * az;
        float d1 = mm1 + bx * bx + by * by + bz * bz;
        out[O_MASK + n]        = (d0 < THRESH2) ? 1.f : 0.f;
        out[O_MASK + NPTS + n] = (d1 < THRESH2) ? 1.f : 0.f;
    }
}

// ---------------- kernel 2: trilinear + skinning, 2 lanes / pair -------------
// t -> pair p = t>>1, half hf = t&1 (12 channels each).  Cells are 128B-line-
// aligned so both lanes of a pair hit the SAME line per corner (3 float4 each).
// Partials (16 acc + wsum) merged via one __shfl_xor(,1); even lane writes.
__global__ __launch_bounds__(256, 6) void deform_kernel(
    const float* __restrict__ pts_in,    // [2,N,3]
    const float* __restrict__ shape_off, // [6890,3]
    const int*   __restrict__ init_idx,  // [N,3]
    const float* __restrict__ init_bar,  // [N,3]
    const float* __restrict__ gT,        // [64^3][32] fp32 padded
    const float* __restrict__ tfs,       // [2,24,4,4]
    const float* __restrict__ gscale,    // [3]
    const float* __restrict__ goff,      // [3]
    float* __restrict__ out) {
    __shared__ float s_tfs[NB * NJ * 16];   // 3 KB

    const int tid = threadIdx.x;
    for (int i = tid; i < NB * NJ * 16; i += 256) s_tfs[i] = tfs[i];
    __syncthreads();

    const int t  = blockIdx.x * 256 + tid;
    const int p  = t >> 1;          // pair id
    const int hf = t & 1;           // channel half
    const int b  = p >> 16;         // block-uniform (boundary at block 512)
    const int n  = p & (NPTS - 1);

    const float* P = pts_in + ((size_t)b * NPTS + n) * 3;
    const float px = P[0], py = P[1], pz = P[2];

    // barycentric shape offset (both lanes of the pair compute identically)
    int i0 = init_idx[n * 3 + 0] * 3;
    int i1 = init_idx[n * 3 + 1] * 3;
    int i2 = init_idx[n * 3 + 2] * 3;
    float b0 = init_bar[n * 3 + 0], b1 = init_bar[n * 3 + 1], b2 = init_bar[n * 3 + 2];
    float qx = px + b0 * shape_off[i0 + 0] + b1 * shape_off[i1 + 0] + b2 * shape_off[i2 + 0];
    float qy = py + b0 * shape_off[i0 + 1] + b1 * shape_off[i1 + 1] + b2 * shape_off[i2 + 1];
    float qz = pz + b0 * shape_off[i0 + 2] + b1 * shape_off[i1 + 2] + b2 * shape_off[i2 + 2];

    float ccx = fminf(fmaxf((qx - goff[0]) * gscale[0], -1.f), 1.f);
    float ccy = fminf(fmaxf((qy - goff[1]) * gscale[1], -1.f), 1.f);
    float ccz = fminf(fmaxf((qz - goff[2]) * gscale[2], -1.f), 1.f);
    float x = (ccx + 1.f) * 0.5f * (GR - 1);
    float y = (ccy + 1.f) * 0.5f * (GR - 1);
    float z = (ccz + 1.f) * 0.5f * (GR - 1);
    int x0 = (int)floorf(x), y0 = (int)floorf(y), z0 = (int)floorf(z);
    int x1 = min(x0 + 1, GR - 1), y1 = min(y0 + 1, GR - 1), z1 = min(z0 + 1, GR - 1);
    float fx = x - (float)x0, fy = y - (float)y0, fz = z - (float)z0;
    float wxa[2] = {1.f - fx, fx}, wya[2] = {1.f - fy, fy}, wza[2] = {1.f - fz, fz};

    float w[12];
#pragma unroll
    for (int c = 0; c < 12; ++c) w[c] = 0.f;

#pragma unroll
    for (int ci = 0; ci < 8; ++ci) {
        int xi = (ci & 1) ? x1 : x0;
        int yi = (ci & 2) ? y1 : y0;
        int zi = (ci & 4) ? z1 : z0;
        float wt = wxa[ci & 1] * wya[(ci >> 1) & 1] * wza[(ci >> 2) & 1];
        int vox = (zi * GR + yi) * GR + xi;
        const float4* g4 = (const float4*)(gT + (size_t)vox * CSTRIDE + hf * 12);
        float4 g0 = g4[0], g1 = g4[1], g2 = g4[2];
        w[0]  = fmaf(wt, g0.x, w[0]);  w[1]  = fmaf(wt, g0.y, w[1]);
        w[2]  = fmaf(wt, g0.z, w[2]);  w[3]  = fmaf(wt, g0.w, w[3]);
        w[4]  = fmaf(wt, g1.x, w[4]);  w[5]  = fmaf(wt, g1.y, w[5]);
        w[6]  = fmaf(wt, g1.z, w[6]);  w[7]  = fmaf(wt, g1.w, w[7]);
        w[8]  = fmaf(wt, g2.x, w[8]);  w[9]  = fmaf(wt, g2.y, w[9]);
        w[10] = fmaf(wt, g2.z, w[10]); w[11] = fmaf(wt, g2.w, w[11]);
    }
    float wsum = 0.f;
#pragma unroll
    for (int c = 0; c < 12; ++c) wsum += w[c];

    // partial skinning over this half's 12 joints; tfs rows from LDS
    // (address depends only on b, hf -> 2 distinct addresses -> free broadcast)
    float4 A0 = make_float4(0.f, 0.f, 0.f, 0.f);
    float4 A1 = A0, A2 = A0, A3 = A0;
    const float4* tb = (const float4*)(s_tfs + (size_t)(b * NJ + hf * 12) * 16);
#pragma unroll
    for (int jj = 0; jj < 12; ++jj) {
        float wj = w[jj];
        float4 r0 = tb[jj * 4 + 0], r1 = tb[jj * 4 + 1];
        float4 r2 = tb[jj * 4 + 2], r3 = tb[jj * 4 + 3];
        A0.x = fmaf(wj, r0.x, A0.x); A0.y = fmaf(wj, r0.y, A0.y);
        A0.z = fmaf(wj, r0.z, A0.z); A0.w = fmaf(wj, r0.w, A0.w);
        A1.x = fmaf(wj, r1.x, A1.x); A1.y = fmaf(wj, r1.y, A1.y);
        A1.z = fmaf(wj, r1.z, A1.z); A1.w = fmaf(wj, r1.w, A1.w);
        A2.x = fmaf(wj, r2.x, A2.x); A2.y = fmaf(wj, r2.y, A2.y);
        A2.z = fmaf(wj, r2.z, A2.z); A2.w = fmaf(wj, r2.w, A2.w);
        A3.x = fmaf(wj, r3.x, A3.x); A3.y = fmaf(wj, r3.y, A3.y);
        A3.z = fmaf(wj, r3.z, A3.z); A3.w = fmaf(wj, r3.w, A3.w);
    }

    // merge halves (lanes 2p, 2p+1)
#define QRED(v) v += __shfl_xor(v, 1)
    QRED(A0.x); QRED(A0.y); QRED(A0.z); QRED(A0.w);
    QRED(A1.x); QRED(A1.y); QRED(A1.z); QRED(A1.w);
    QRED(A2.x); QRED(A2.y); QRED(A2.z); QRED(A2.w);
    QRED(A3.x); QRED(A3.y); QRED(A3.z); QRED(A3.w);
    QRED(wsum);
#undef QRED

    if (hf == 0) {
        float inv = __builtin_amdgcn_rcpf(fmaxf(wsum, 1e-6f));
        A0.x *= inv; A0.y *= inv; A0.z *= inv; A0.w *= inv;
        A1.x *= inv; A1.y *= inv; A1.z *= inv; A1.w *= inv;
        A2.x *= inv; A2.y *= inv; A2.z *= inv; A2.w *= inv;
        A3.x *= inv; A3.y *= inv; A3.z *= inv; A3.w *= inv;

        float ox = A0.x * qx + A0.y * qy + A0.z * qz + A0.w;
        float oy = A1.x * qx + A1.y * qy + A1.z * qz + A1.w;
        float oz = A2.x * qx + A2.y * qy + A2.z * qz + A2.w;

        size_t bn = (size_t)p;   // p == b*NPTS + n
        out[O_PTS + bn * 3 + 0] = ox;
        out[O_PTS + bn * 3 + 1] = oy;
        out[O_PTS + bn * 3 + 2] = oz;
        float4* wt4 = (float4*)(out + O_WTF + bn * 16);
        wt4[0] = A0; wt4[1] = A1; wt4[2] = A2; wt4[3] = A3;
    }
}

// ---------------- fallback (ws too small): simple fp32 path ----------------
__global__ __launch_bounds__(256) void snarf_fallback(
    const float* __restrict__ pts_in, const float* __restrict__ vs,
    const float* __restrict__ shape_off, const int* __restrict__ init_idx,
    const float* __restrict__ init_bar, const float* __restrict__ grid,
    const float* __restrict__ tfs, const float* __restrict__ gscale,
    const float* __restrict__ goff, float* __restrict__ out) {
    const int n = blockIdx.x * 256 + threadIdx.x;
    for (int b = 0; b < NB; ++b) {
        float px = pts_in[((size_t)b * NPTS + n) * 3 + 0];
        float py = pts_in[((size_t)b * NPTS + n) * 3 + 1];
        float pz = pts_in[((size_t)b * NPTS + n) * 3 + 2];
        float mm = 3.4e38f;
        for (int v = 0; v < NVSUB; ++v) {
            float dx = px - vs[v * 3 + 0], dy = py - vs[v * 3 + 1], dz = pz - vs[v * 3 + 2];
            mm = fminf(mm, dx * dx + dy * dy + dz * dz);
        }
        int i0 = init_idx[n * 3 + 0] * 3, i1 = init_idx[n * 3 + 1] * 3, i2 = init_idx[n * 3 + 2] * 3;
        float b0 = init_bar[n * 3 + 0], b1 = init_bar[n * 3 + 1], b2 = init_bar[n * 3 + 2];
        float qx = px + b0 * shape_off[i0 + 0] + b1 * shape_off[i1 + 0] + b2 * shape_off[i2 + 0];
        float qy = py + b0 * shape_off[i0 + 1] + b1 * shape_off[i1 + 1] + b2 * shape_off[i2 + 1];
        float qz = pz + b0 * shape_off[i0 + 2] + b1 * shape_off[i1 + 2] + b2 * shape_off[i2 + 2];
        float cx = fminf(fmaxf((qx - goff[0]) * gscale[0], -1.f), 1.f);
        float cy = fminf(fmaxf((qy - goff[1]) * gscale[1], -1.f), 1.f);
        float cz = fminf(fmaxf((qz - goff[2]) * gscale[2], -1.f), 1.f);
        float x = (cx + 1.f) * 0.5f * (GR - 1), y = (cy + 1.f) * 0.5f * (GR - 1), z = (cz + 1.f) * 0.5f * (GR - 1);
        int x0 = (int)floorf(x), y0 = (int)floorf(y), z0 = (int)floorf(z);
        int x1 = min(x0 + 1, GR - 1), y1 = min(y0 + 1, GR - 1), z1 = min(z0 + 1, GR - 1);
        float fx = x - x0, fy = y - y0, fz = z - z0;
        float wxa[2] = {1.f - fx, fx}, wya[2] = {1.f - fy, fy}, wza[2] = {1.f - fz, fz};
        float w[NJ];
        for (int c = 0; c < NJ; ++c) w[c] = 0.f;
        for (int ci = 0; ci < 8; ++ci) {
            int xi = (ci & 1) ? x1 : x0, yi = (ci & 2) ? y1 : y0, zi = (ci & 4) ? z1 : z0;
            float wt = wxa[ci & 1] * wya[(ci >> 1) & 1] * wza[(ci >> 2) & 1];
            int vox = (zi * GR + yi) * GR + xi;
            for (int c = 0; c < NJ; ++c) w[c] = fmaf(wt, grid[c * GRV + vox], w[c]);
        }
        float s = 0.f;
        for (int c = 0; c < NJ; ++c) s += w[c];
        float inv = 1.f / fmaxf(s, 1e-6f);
        float acc[16];
        for (int k = 0; k < 16; ++k) acc[k] = 0.f;
        for (int j = 0; j < NJ; ++j) {
            float wj = w[j] * inv;
            for (int k = 0; k < 16; ++k) acc[k] = fmaf(wj, tfs[(b * NJ + j) * 16 + k], acc[k]);
        }
        size_t bn = (size_t)b * NPTS + n;
        out[O_PTS + bn * 3 + 0] = acc[0] * qx + acc[1] * qy + acc[2] * qz + acc[3];
        out[O_PTS + bn * 3 + 1] = acc[4] * qx + acc[5] * qy + acc[6] * qz + acc[7];
        out[O_PTS + bn * 3 + 2] = acc[8] * qx + acc[9] * qy + acc[10] * qz + acc[11];
        out[O_MASK + bn] = (mm < THRESH2) ? 1.f : 0.f;
        for (int k = 0; k < 16; ++k) out[O_WTF + bn * 16 + k] = acc[k];
    }
}

extern "C" void kernel_launch(void* const* d_in, const int* in_sizes, int n_in,
                              void* d_out, int out_size, void* d_ws, size_t ws_size,
                              hipStream_t stream) {
    const float* pts_in    = (const float*)d_in[0];
    const float* vs        = (const float*)d_in[1];
    const float* shape_off = (const float*)d_in[2];
    const int*   init_idx  = (const int*)d_in[3];
    const float* init_bar  = (const float*)d_in[4];
    const float* lbs       = (const float*)d_in[5];
    const float* tfs       = (const float*)d_in[6];
    const float* gs        = (const float*)d_in[7];
    const float* go        = (const float*)d_in[8];
    float* out = (float*)d_out;

    const size_t needed = (size_t)GRV * CSTRIDE * sizeof(float);  // 33.6 MB
    if (ws_size >= needed) {
        float* gT = (float*)d_ws;
        prep_mask_kernel<<<PREP_BLOCKS + MASK_BLOCKS, 256, 0, stream>>>(
            lbs, gT, pts_in, vs, out);
        deform_kernel<<<(NB * NPTS * 2) / 256, 256, 0, stream>>>(
            pts_in, shape_off, init_idx, init_bar, gT, tfs, gs, go, out);
    } else {
        snarf_fallback<<<NPTS / 256, 256, 0, stream>>>(
            pts_in, vs, shape_off, init_idx, init_bar, lbs, tfs, gs, go, out);
    }
}